// Round 5
// baseline (64.658 us; speedup 1.0000x reference)
//
#include <hip/hip_runtime.h>

// YOLOv1 loss, MI355X. input/target (4096,14,14,30) f32 -> scalar f32 (loss/4096).
// Round 5: same as round-4 plan but staging uses ONLY HW-verified global_load_lds
// widths (16 and 4; width 12 returned garbage -> NaN in round 4).
// Per 3840 B tensor-chunk: 3x 16B-wide instr (3072 B) + 3x 4B-wide instr (768 B).
// 32-cell chunks, 15,360 B LDS/block -> 10 one-wave blocks/CU, counted vmcnt(12)
// double-buffer, zero barriers. 2 lanes/cell; stride-15-dword LDS reads
// (gcd(15,32)=1 -> conflict-free 2-way).

#define COORD 5.0f
#define NOOBJ 0.5f

#define NCELLS   (4096 * 14 * 14)   // 802816
#define CPC      32                 // cells per chunk (per wave)
#define CHB      (CPC * 120)        // 3840 B per tensor per chunk
#define NCHUNKS  (NCELLS / CPC)     // 25088
#define GRID     2560               // 10 blocks/CU; ~9.8 chunks per wave

__device__ __forceinline__ float d2f(float a, float b) { float d = a - b; return d * d; }
__device__ __forceinline__ float sqd(float a, float b) {
    // (sqrt(a)-sqrt(b))^2 = a + b - 2*sqrt(a*b);  a,b >= 0
    return a + b - 2.0f * sqrtf(a * b);
}

__global__ __launch_bounds__(64) void yolo_loss_kernel(
    const float* __restrict__ inp,
    const float* __restrict__ tgt,
    float* __restrict__ out,
    float inv_n)
{
    __shared__ __align__(16) char smem[2][2][CHB];   // [dbuf][tensor][bytes] = 15360 B
    const int lane = threadIdx.x;

    auto stage = [&](int b, int c) {
        const char* gi = (const char*)inp + (size_t)c * CHB;
        const char* gt = (const char*)tgt + (size_t)c * CHB;
        char* li = &smem[b][0][0];
        char* lt = &smem[b][1][0];
        // 3 x 16B-wide: bytes [0, 3072)
#pragma unroll
        for (int k = 0; k < 3; ++k) {
            __builtin_amdgcn_global_load_lds(
                (const __attribute__((address_space(1))) void*)(gi + k * 1024 + lane * 16),
                (__attribute__((address_space(3))) void*)(li + k * 1024), 16, 0, 0);
            __builtin_amdgcn_global_load_lds(
                (const __attribute__((address_space(1))) void*)(gt + k * 1024 + lane * 16),
                (__attribute__((address_space(3))) void*)(lt + k * 1024), 16, 0, 0);
        }
        // 3 x 4B-wide: bytes [3072, 3840)
#pragma unroll
        for (int k = 0; k < 3; ++k) {
            __builtin_amdgcn_global_load_lds(
                (const __attribute__((address_space(1))) void*)(gi + 3072 + k * 256 + lane * 4),
                (__attribute__((address_space(3))) void*)(li + 3072 + k * 256), 4, 0, 0);
            __builtin_amdgcn_global_load_lds(
                (const __attribute__((address_space(1))) void*)(gt + 3072 + k * 256 + lane * 4),
                (__attribute__((address_space(3))) void*)(lt + 3072 + k * 256), 4, 0, 0);
        }
    };

    float acc = 0.0f;
    int c = blockIdx.x;              // GRID <= NCHUNKS, always valid
    stage(0, c);
    int buf = 0;

    const int p = lane >> 1;         // cell within chunk (2 lanes per cell)
    const int half = lane & 1;

    for (; c < NCHUNKS; c += GRID) {
        const int cn = c + GRID;
        if (cn < NCHUNKS) {
            stage(buf ^ 1, cn);
            asm volatile("s_waitcnt vmcnt(12)" ::: "memory");   // current chunk landed
        } else {
            asm volatile("s_waitcnt vmcnt(0)" ::: "memory");
        }

        const float* li = (const float*)&smem[buf][0][0];
        const float* lt = (const float*)&smem[buf][1][0];
        const float* ip = li + 15 * lane;    // this lane's 15 channels
        const float* tp = lt + 15 * lane;

        // masks from target conf (pair-broadcast read, conflict-free)
        float t0 = lt[p * 30];
        float t1 = lt[p * 30 + 1];
        bool o0 = (t0 == 1.0f), o1 = (t1 == 1.0f);
        float f0 = o0 ? 1.0f : 0.0f;
        float f1 = (o1 && !o0) ? 1.0f : 0.0f;
        float h  = (o0 || o1) ? 1.0f : 0.0f;
        float nf = 1.0f - h;

        if (half == 0) {
            // channels 0..14: conf0 conf1 | x0 y0 w0 h0 | x1 y1 w1 h1 | cls0..cls4
            float s0  = d2f(ip[0], tp[0]);
            float s1  = d2f(ip[1], tp[1]);
            float xy0 = d2f(ip[2], tp[2]) + d2f(ip[3], tp[3]);
            float wh0 = sqd(ip[4], tp[4]) + sqd(ip[5], tp[5]);
            float xy1 = d2f(ip[6], tp[6]) + d2f(ip[7], tp[7]);
            float wh1 = sqd(ip[8], tp[8]) + sqd(ip[9], tp[9]);
            float cls = d2f(ip[10], tp[10]) + d2f(ip[11], tp[11]) + d2f(ip[12], tp[12])
                      + d2f(ip[13], tp[13]) + d2f(ip[14], tp[14]);
            acc += COORD * (f0 * (xy0 + wh0) + f1 * (xy1 + wh1))
                 + f0 * s0 + f1 * s1
                 + NOOBJ * nf * (s0 + s1)
                 + h * cls;
        } else {
            // channels 15..29: cls5..cls19
            float cls = 0.0f;
#pragma unroll
            for (int j = 0; j < 15; ++j)
                cls += d2f(ip[j], tp[j]);
            acc += h * cls;
        }

        buf ^= 1;
    }

    // ---- wave reduce (block == 1 wave) ----
#pragma unroll
    for (int off = 32; off > 0; off >>= 1)
        acc += __shfl_down(acc, off, 64);
    if (lane == 0) atomicAdd(out, acc * inv_n);
}

extern "C" void kernel_launch(void* const* d_in, const int* in_sizes, int n_in,
                              void* d_out, int out_size, void* d_ws, size_t ws_size,
                              hipStream_t stream) {
    const float* inp = (const float*)d_in[0];
    const float* tgt = (const float*)d_in[1];
    float* out = (float*)d_out;

    hipMemsetAsync(out, 0, sizeof(float), stream);
    yolo_loss_kernel<<<GRID, 64, 0, stream>>>(inp, tgt, out, 1.0f / 4096.0f);
}

// Round 6
// 44.976 us; speedup vs baseline: 1.4376x; 1.4376x over previous
//
#include <hip/hip_runtime.h>

// YOLOv1 loss, MI355X. input/target (4096,14,14,30) f32 -> scalar f32 (loss/4096).
// Round 6: R3 structure (width-16-only global_load_lds, 128-cell chunks, async
// counted-vmcnt double-buffer) with its two measured defects fixed:
//  (a) compute uses 2-lanes-per-cell stride-15-dword LDS reads (R5-validated,
//      0 bank conflicts) instead of 240B-stride ds_read_b128 (8-way, 1.84M cyc);
//  (b) 128-thread blocks: wave0 stages tensor I (15 instr), wave1 stages T (15)
//      -> uniform vmcnt(15), 2 raw s_barriers/iter, GRID=512 -> 2 blocks/CU =
//      4 waves/CU (2x R3) with 60-120KB in flight per CU.

#define COORD 5.0f
#define NOOBJ 0.5f

#define NCELLS   (4096 * 14 * 14)   // 802816
#define CPC      128                // cells per chunk
#define CHB      (CPC * 120)        // 15360 B per tensor per chunk
#define NCHUNKS  (NCELLS / CPC)     // 6272
#define GRID     512                // 2 blocks/CU resident; 12-13 chunks/block
#define THREADS  128

__device__ __forceinline__ float d2f(float a, float b) { float d = a - b; return d * d; }
__device__ __forceinline__ float sqd(float a, float b) {
    // (sqrt(a)-sqrt(b))^2 = a + b - 2*sqrt(a*b);  a,b >= 0
    return a + b - 2.0f * sqrtf(a * b);
}

__global__ __launch_bounds__(THREADS) void yolo_loss_kernel(
    const float* __restrict__ inp,
    const float* __restrict__ tgt,
    float* __restrict__ out,
    float inv_n)
{
    __shared__ __align__(16) char smem[2][2][CHB];   // [dbuf][tensor][bytes] = 61440 B
    __shared__ float wsum[2];

    const int tid  = threadIdx.x;
    const int lane = tid & 63;
    const int wid  = tid >> 6;       // 0: stages input, 1: stages target

    const char* gsrc0 = (const char*)(wid == 0 ? inp : tgt) + (size_t)lane * 16;

    // wave `wid` stages its tensor's 15360B chunk as 15 width-16 instructions
    auto stage = [&](int b, int c) {
        const char* g = gsrc0 + (size_t)c * CHB;
        char* l = &smem[b][wid][0];
#pragma unroll
        for (int k = 0; k < 15; ++k) {
            __builtin_amdgcn_global_load_lds(
                (const __attribute__((address_space(1))) void*)(g + k * 1024),
                (__attribute__((address_space(3))) void*)(l + k * 1024), 16, 0, 0);
        }
    };

    float acc = 0.0f;
    int c = blockIdx.x;              // GRID <= NCHUNKS, always valid
    stage(0, c);
    int buf = 0;

    const int half = lane & 1;

    for (; c < NCHUNKS; c += GRID) {
        const int cn = c + GRID;
        if (cn < NCHUNKS) {
            stage(buf ^ 1, cn);
            asm volatile("s_waitcnt vmcnt(15)" ::: "memory");   // my prev-chunk loads landed
        } else {
            asm volatile("s_waitcnt vmcnt(0)" ::: "memory");
        }
        asm volatile("s_barrier" ::: "memory");                 // both tensors visible

        const float* li = (const float*)&smem[buf][0][0];
        const float* lt = (const float*)&smem[buf][1][0];

#pragma unroll
        for (int pass = 0; pass < 2; ++pass) {
            const int p = (lane >> 1) + 32 * pass + 64 * wid;   // cell 0..127
            const int base = 15 * lane + 960 * pass + 1920 * wid; // = 30p + 15*half
            const float* ip = li + base;
            const float* tp = lt + base;

            // masks from target conf (pair-broadcast reads, conflict-free)
            float t0 = lt[p * 30];
            float t1 = lt[p * 30 + 1];
            bool o0 = (t0 == 1.0f), o1 = (t1 == 1.0f);
            float f0 = o0 ? 1.0f : 0.0f;
            float f1 = (o1 && !o0) ? 1.0f : 0.0f;
            float h  = (o0 || o1) ? 1.0f : 0.0f;
            float nf = 1.0f - h;

            if (half == 0) {
                // channels 0..14: conf0 conf1 | x0 y0 w0 h0 | x1 y1 w1 h1 | cls0..4
                float s0  = d2f(ip[0], tp[0]);
                float s1  = d2f(ip[1], tp[1]);
                float xy0 = d2f(ip[2], tp[2]) + d2f(ip[3], tp[3]);
                float wh0 = sqd(ip[4], tp[4]) + sqd(ip[5], tp[5]);
                float xy1 = d2f(ip[6], tp[6]) + d2f(ip[7], tp[7]);
                float wh1 = sqd(ip[8], tp[8]) + sqd(ip[9], tp[9]);
                float cls = d2f(ip[10], tp[10]) + d2f(ip[11], tp[11]) + d2f(ip[12], tp[12])
                          + d2f(ip[13], tp[13]) + d2f(ip[14], tp[14]);
                acc += COORD * (f0 * (xy0 + wh0) + f1 * (xy1 + wh1))
                     + f0 * s0 + f1 * s1
                     + NOOBJ * nf * (s0 + s1)
                     + h * cls;
            } else {
                // channels 15..29: cls5..cls19
                float cls = 0.0f;
#pragma unroll
                for (int j = 0; j < 15; ++j)
                    cls += d2f(ip[j], tp[j]);
                acc += h * cls;
            }
        }

        asm volatile("s_barrier" ::: "memory");  // all reads of buf done before overwrite
        buf ^= 1;
    }

    // ---- reduction: wave shfl -> LDS -> one atomic per block ----
#pragma unroll
    for (int off = 32; off > 0; off >>= 1)
        acc += __shfl_down(acc, off, 64);
    if (lane == 0) wsum[wid] = acc;
    __syncthreads();
    if (tid == 0) atomicAdd(out, (wsum[0] + wsum[1]) * inv_n);
}

extern "C" void kernel_launch(void* const* d_in, const int* in_sizes, int n_in,
                              void* d_out, int out_size, void* d_ws, size_t ws_size,
                              hipStream_t stream) {
    const float* inp = (const float*)d_in[0];
    const float* tgt = (const float*)d_in[1];
    float* out = (float*)d_out;

    hipMemsetAsync(out, 0, sizeof(float), stream);
    yolo_loss_kernel<<<GRID, THREADS, 0, stream>>>(inp, tgt, out, 1.0f / 4096.0f);
}